// Round 3
// baseline (365.634 us; speedup 1.0000x reference)
//
#include <hip/hip_runtime.h>

typedef unsigned short u16;
typedef __bf16 bf16x8 __attribute__((ext_vector_type(8)));
typedef float f32x4 __attribute__((ext_vector_type(4)));
typedef float f32x16 __attribute__((ext_vector_type(16)));

#define AS1U(p) ((__attribute__((address_space(1))) unsigned int*)(p))
#define AS3U(p) ((__attribute__((address_space(3))) unsigned int*)(p))

__device__ __forceinline__ u16 f2bf(float f) {  // round-to-nearest-even
  union { float f; unsigned int i; } c; c.f = f;
  return (u16)((c.i + 0x7FFFu + ((c.i >> 16) & 1u)) >> 16);
}
__device__ __forceinline__ u16 f2bf_trunc(float f) {
  union { float f; unsigned int i; } c; c.f = f;
  return (u16)(c.i >> 16);
}
// pack two f32 -> bf16x2 word (no builtin on gfx950; RNE)
__device__ __forceinline__ unsigned cvt_pk_bf16(float lo, float hi) {
  unsigned r;
  asm("v_cvt_pk_bf16_f32 %0, %1, %2" : "=v"(r) : "v"(lo), "v"(hi));
  return r;
}
// swap a's upper 32 lanes with b's lower 32 lanes (both modified)
__device__ __forceinline__ void plswap(unsigned& a, unsigned& b) {
  asm("v_permlane32_swap_b32 %0, %1" : "+v"(a), "+v"(b));
}

// ---------------------------------------------------------------------------
// Deep-pipelined GEMM: C = A @ Bt^T + bias (+relu, +res). 256x128 tile, BK=64,
// 512 threads = 8 waves (4M x 2N, per-wave 64x64), mfma_f32_32x32x16_bf16.
// TRIPLE-buffered LDS (144 KB): iter kt reads slot kt%3, stages kt+2 into
// (kt+2)%3 (free since kt-1's barrier). Boundary: s_waitcnt vmcnt(6) — the
// just-issued 6 loads of kt+2 stay in flight across the raw s_barrier; only
// kt+1's 6 are completed. Never drains to 0 in steady state (T3+T4).
// chunk^(row&7) 16B swizzle both sides (8 lanes/chunk-group per b128 read —
// bank-uniform). Requires K % 64 == 0, K/64 >= 2. OMODE: 0 fp32, 2 bf16 out.
// ---------------------------------------------------------------------------
template <int OMODE>
__global__ __launch_bounds__(512, 2) void gemm3(
    const u16* __restrict__ A, long lda,
    const u16* __restrict__ B, long ldb,
    void* __restrict__ Cv, long ldc,
    int K, const float* __restrict__ bias,
    const float* __restrict__ res, long ldres, int relu) {
  __shared__ u16 As[3][256 * 64];
  __shared__ u16 Bs[3][128 * 64];
  const int t = threadIdx.x;
  const int w = t >> 6, l = t & 63;
  const int hi = l >> 5, lq = l & 31;
  const int wm = w >> 1, wn = w & 1;
  const long row0 = (long)blockIdx.x * 256;
  const long col0 = (long)blockIdx.y * 128;

  auto stage = [&](int slot, int k0) {
#pragma unroll
    for (int i = 0; i < 4; i++) {
      int s = t + i * 512, r = s >> 3, c = s & 7;
      __builtin_amdgcn_global_load_lds(AS1U(A + (row0 + r) * lda + k0 + (c ^ (r & 7)) * 8),
                                       AS3U(&As[slot][s * 8]), 16, 0, 0);
    }
#pragma unroll
    for (int i = 0; i < 2; i++) {
      int s = t + i * 512, r = s >> 3, c = s & 7;
      __builtin_amdgcn_global_load_lds(AS1U(B + (col0 + r) * ldb + k0 + (c ^ (r & 7)) * 8),
                                       AS3U(&Bs[slot][s * 8]), 16, 0, 0);
    }
  };

  f32x16 acc[2][2] = {};
  const int NT = K >> 6;

  stage(0, 0);
  stage(1, 64);
  asm volatile("s_waitcnt vmcnt(6)" ::: "memory");  // slot0 complete; slot1 in flight
  __builtin_amdgcn_s_barrier();
  __builtin_amdgcn_sched_barrier(0);

  int s0 = 0, s1 = 1, s2 = 2;
  for (int kt = 0; kt < NT; kt++) {
    if (kt + 2 < NT) stage(s2, (kt + 2) * 64);
    bf16x8 a[2][4], b[2][4];
#pragma unroll
    for (int mi = 0; mi < 2; mi++) {
      const int r = wm * 64 + mi * 32 + lq;
#pragma unroll
      for (int kk = 0; kk < 4; kk++)
        a[mi][kk] = *(const bf16x8*)&As[s0][(r * 8 + ((kk * 2 + hi) ^ (r & 7))) * 8];
    }
#pragma unroll
    for (int nj = 0; nj < 2; nj++) {
      const int r = wn * 64 + nj * 32 + lq;
#pragma unroll
      for (int kk = 0; kk < 4; kk++)
        b[nj][kk] = *(const bf16x8*)&Bs[s0][(r * 8 + ((kk * 2 + hi) ^ (r & 7))) * 8];
    }
    __builtin_amdgcn_s_setprio(1);
#pragma unroll
    for (int kk = 0; kk < 4; kk++)
#pragma unroll
      for (int mi = 0; mi < 2; mi++)
#pragma unroll
        for (int nj = 0; nj < 2; nj++)
          acc[mi][nj] = __builtin_amdgcn_mfma_f32_32x32x16_bf16(a[mi][kk], b[nj][kk], acc[mi][nj], 0, 0, 0);
    __builtin_amdgcn_s_setprio(0);
    if (kt + 2 < NT) {
      asm volatile("s_waitcnt vmcnt(6)" ::: "memory");  // kt+1 complete; kt+2 in flight
    } else {
      asm volatile("s_waitcnt vmcnt(0)" ::: "memory");  // tail drain (once)
    }
    __builtin_amdgcn_s_barrier();
    __builtin_amdgcn_sched_barrier(0);
    const int tmp = s0; s0 = s1; s1 = s2; s2 = tmp;
  }

  // epilogue: C layout col=lq, row=(g&3)+8*(g>>2)+4*hi per 32x32 tile
#pragma unroll
  for (int nj = 0; nj < 2; nj++) {
    const long gn = col0 + wn * 64 + nj * 32 + lq;
    const float bv = bias ? bias[gn] : 0.0f;
#pragma unroll
    for (int mi = 0; mi < 2; mi++) {
#pragma unroll
      for (int g = 0; g < 16; g++) {
        const long gm = row0 + wm * 64 + mi * 32 + (g & 3) + 8 * (g >> 2) + 4 * hi;
        float v = acc[mi][nj][g] + bv;
        if (relu && v < 0.0f) v = 0.0f;
        if (res) v += res[gm * ldres + gn];
        if (OMODE == 0) ((float*)Cv)[gm * ldc + gn] = v;
        else ((u16*)Cv)[gm * ldc + gn] = f2bf(v);
      }
    }
  }
}

// ---------------------------------------------------------------------------
// C = scale*(A @ Bt^T) + bias (+relu, +res). Single-plane bf16, 1 MFMA/product.
// Double-buffered K-loop. BK=32: m97-plain LDS (64B rows). BK=64: flash-style
// 128B rows with chunk^(row&7) swizzle (measured conflict-free) — halves the
// barrier count vs BK=32. K % (2*BK) == 0. OMODE: 0 = fp32 out, 2 = bf16 out.
// ---------------------------------------------------------------------------
template <int BM, int BN, int BK, int OMODE>
__global__ __launch_bounds__(256) void gemm_bt(
    const u16* __restrict__ A, long lda,
    const u16* __restrict__ B, long ldb,
    void* __restrict__ Cv, long ldc,
    int K, float scale, const float* __restrict__ bias,
    const float* __restrict__ res, long ldres, int relu) {
  constexpr int WN = (BN == 128) ? 64 : 32;
  constexpr int MI = 4, NJ = WN / 16;
  constexpr int KK = BK / 32;  // k-chunks per stage
  __shared__ u16 As0[BM * BK], As1[BM * BK];
  __shared__ u16 Bs0[BN * BK], Bs1[BN * BK];
  const int t = threadIdx.x;
  const int w = t >> 6, l = t & 63;
  const int wr = w >> 1, wc = w & 1;
  const int quad = l >> 4, mlo = l & 15;
  const long row0 = (long)blockIdx.x * BM;
  const long col0 = (long)blockIdx.y * BN;

  f32x4 acc[MI][NJ] = {};

  auto stage = [&](u16 (&Ad)[BM * BK], u16 (&Bd)[BN * BK], int k0) {
    if (BK == 32) {
#pragma unroll
      for (int i = 0; i < BM / 64; i++) {
        int s = t + i * 256, r = s >> 2, c = s & 3;
        const u16* g = A + (row0 + r) * lda + k0 + c * 8;
        __builtin_amdgcn_global_load_lds(AS1U(g), AS3U(&Ad[s * 8]), 16, 0, 0);
      }
#pragma unroll
      for (int i = 0; i < BN / 64; i++) {
        int s = t + i * 256, r = s >> 2, c = s & 3;
        const u16* g = B + (col0 + r) * ldb + k0 + c * 8;
        __builtin_amdgcn_global_load_lds(AS1U(g), AS3U(&Bd[s * 8]), 16, 0, 0);
      }
    } else {  // BK == 64: 128B rows, chunk^(r&7) swizzle
#pragma unroll
      for (int i = 0; i < BM / 32; i++) {
        int s = t + i * 256, r = s >> 3, c = s & 7;
        const u16* g = A + (row0 + r) * lda + k0 + (c ^ (r & 7)) * 8;
        __builtin_amdgcn_global_load_lds(AS1U(g), AS3U(&Ad[s * 8]), 16, 0, 0);
      }
#pragma unroll
      for (int i = 0; i < BN / 32; i++) {
        int s = t + i * 256, r = s >> 3, c = s & 7;
        const u16* g = B + (col0 + r) * ldb + k0 + (c ^ (r & 7)) * 8;
        __builtin_amdgcn_global_load_lds(AS1U(g), AS3U(&Bd[s * 8]), 16, 0, 0);
      }
    }
  };
  auto compute = [&](const u16 (&Asr)[BM * BK], const u16 (&Bsr)[BN * BK]) {
#pragma unroll
    for (int kk = 0; kk < KK; kk++) {
      bf16x8 a[MI], b[NJ];
#pragma unroll
      for (int i = 0; i < MI; i++) {
        int r = wr * 64 + i * 16 + mlo;
        a[i] = (BK == 32) ? *(const bf16x8*)&Asr[(r * 4 + quad) * 8]
                          : *(const bf16x8*)&Asr[(r * 8 + ((kk * 4 + quad) ^ (r & 7))) * 8];
      }
#pragma unroll
      for (int j = 0; j < NJ; j++) {
        int r = wc * WN + j * 16 + mlo;
        b[j] = (BK == 32) ? *(const bf16x8*)&Bsr[(r * 4 + quad) * 8]
                          : *(const bf16x8*)&Bsr[(r * 8 + ((kk * 4 + quad) ^ (r & 7))) * 8];
      }
#pragma unroll
      for (int i = 0; i < MI; i++)
#pragma unroll
        for (int j = 0; j < NJ; j++)
          acc[i][j] = __builtin_amdgcn_mfma_f32_16x16x32_bf16(a[i], b[j], acc[i][j], 0, 0, 0);
    }
  };

  stage(As0, Bs0, 0);
  for (int k0 = 0; k0 < K; k0 += 2 * BK) {
    __syncthreads();
    stage(As1, Bs1, k0 + BK);
    compute(As0, Bs0);
    __syncthreads();
    if (k0 + 2 * BK < K) stage(As0, Bs0, k0 + 2 * BK);
    compute(As1, Bs1);
  }

#pragma unroll
  for (int i = 0; i < MI; i++) {
#pragma unroll
    for (int j = 0; j < NJ; j++) {
      const long gn = col0 + wc * WN + j * 16 + mlo;
      const float bv = bias ? bias[gn] : 0.0f;
#pragma unroll
      for (int r = 0; r < 4; r++) {
        const long gm = row0 + wr * 64 + i * 16 + quad * 4 + r;
        float v = acc[i][j][r] * scale + bv;
        if (relu && v < 0.0f) v = 0.0f;
        if (res) v += res[gm * ldres + gn];
        if (OMODE == 0) ((float*)Cv)[gm * ldc + gn] = v;
        else ((u16*)Cv)[gm * ldc + gn] = f2bf(v);
      }
    }
  }
}

// ---------------------------------------------------------------------------
// Fused flash attention, in-register softmax (T12). Br=128, Bc=64, DK=64.
// Swapped QK^T via mfma_f32_32x32x16_bf16: S^T = K·Q^T so each lane holds a
// lane-local slice (16 of 32 keys per k-tile) of ONE q-row (q = lane&31).
// P never touches LDS: exp2 in f32 regs -> v_cvt_pk_bf16_f32 pairs ->
// v_permlane32_swap_b32 redistributes straight into the PV A-fragment layout.
// Q pre-scaled by 1/8*log2e; mask all-ones bitmap precomputed in prologue;
// both kt score tiles computed back-to-back so SM VALU hides under MFMAs.
// LDS 32 KB (K,V double-buffered only); one barrier/iter.
// ---------------------------------------------------------------------------
__global__ __launch_bounds__(256, 2) void flash_attn(
    const u16* __restrict__ QKV, const u16* __restrict__ VT,
    const int* __restrict__ mask, u16* __restrict__ ctx) {
  __shared__ u16 Ks[2][64 * 64];
  __shared__ u16 Vs[2][64 * 64];
  const int t = threadIdx.x;
  const int w = t >> 6, l = t & 63;
  const int hi = l >> 5, lq = l & 31, rx = lq & 7;
  const int z = blockIdx.z, b = z >> 4, h = z & 15;
  const long q0 = (long)blockIdx.x * 128;
  const u16* Qg = QKV + (long)b * (2048L * 3072) + h * 64;
  const u16* Kg = Qg + 1024;
  const u16* Vg = VT + (long)b * (1024L * 2048) + (long)(h * 64) * 2048;
  const int* mrow = mask + b * 2048;

#pragma unroll
  for (int i = 0; i < 2; i++) {
    int s = t + i * 256, r = s >> 3, c = s & 7;
    __builtin_amdgcn_global_load_lds(AS1U(Kg + (long)r * 3072 + (c ^ (r & 7)) * 8),
                                     AS3U(&Ks[0][s * 8]), 16, 0, 0);
    __builtin_amdgcn_global_load_lds(AS1U(Vg + (long)r * 2048 + (c ^ (r & 7)) * 8),
                                     AS3U(&Vs[0][s * 8]), 16, 0, 0);
  }

  const float CS = 0.125f * 1.44269504f;  // 1/sqrt(64) * log2(e)
  const float CM = -1.44269504f;          // MASK_FILL(-1) * log2(e)

  // Q as QK^T B-fragments, PRE-SCALED by CS: lane holds Q[q=lq][kk*16+hi*8+e]
  bf16x8 aq[4];
#pragma unroll
  for (int kk = 0; kk < 4; kk++) {
    const u16* g = Qg + (q0 + w * 32 + lq) * 3072 + kk * 16 + hi * 8;
    union { uint4 u; bf16x8 v; u16 s[8]; } cc; cc.u = *(const uint4*)g;
#pragma unroll
    for (int e = 0; e < 8; e++) {
      union { unsigned u; float f; } qf; qf.u = (unsigned)cc.s[e] << 16;
      cc.s[e] = f2bf(qf.f * CS);
    }
    aq[kk] = cc.v;
  }

  // prologue mask bitmap: bit it == 1 -> all 64 keys of tile `it` unmasked
  unsigned am = 0;
  for (int it = 0; it < 32; ++it) {
    unsigned long long bmv = __ballot(mrow[it * 64 + l] != 0);
    am |= ((bmv == ~0ull) ? 1u : 0u) << it;
  }

  f32x16 o[2] = {}, den = {};
  union { u16 s[8]; bf16x8 v; } ones;
#pragma unroll
  for (int e = 0; e < 8; e++) ones.s[e] = 0x3F80;

  for (int it = 0; it < 32; ++it) {
    const int cur = it & 1;
    __syncthreads();
    if (it + 1 < 32) {
      const int nb = 1 - cur;
      const u16* Kg2 = Kg + (long)(it + 1) * 64 * 3072;
      const u16* Vg2 = Vg + (it + 1) * 64;
#pragma unroll
      for (int i2 = 0; i2 < 2; i2++) {
        int s = t + i2 * 256, r = s >> 3, c = s & 7;
        __builtin_amdgcn_global_load_lds(AS1U(Kg2 + (long)r * 3072 + (c ^ (r & 7)) * 8),
                                         AS3U(&Ks[nb][s * 8]), 16, 0, 0);
        __builtin_amdgcn_global_load_lds(AS1U(Vg2 + (long)r * 2048 + (c ^ (r & 7)) * 8),
                                         AS3U(&Vs[nb][s * 8]), 16, 0, 0);
      }
    }
    const bool allone = (am >> it) & 1u;
    unsigned long long bm = ~0ull;
    if (!allone) bm = __ballot(mrow[it * 64 + l] != 0);  // rare slow path

    // --- QK^T (swapped) for BOTH kt tiles: S^T[k][q]; A = K rows, B = Q ---
    f32x16 sa[2];
    __builtin_amdgcn_s_setprio(1);
#pragma unroll
    for (int kt = 0; kt < 2; kt++) {
      f32x16 s0 = {};
      const int rk = kt * 32 + lq;
#pragma unroll
      for (int kk = 0; kk < 4; kk++) {
        bf16x8 ak = *(const bf16x8*)&Ks[cur][(rk * 8 + ((2 * kk + hi) ^ rx)) * 8];
        s0 = __builtin_amdgcn_mfma_f32_32x32x16_bf16(ak, aq[kk], s0, 0, 0, 0);
      }
      sa[kt] = s0;
    }
    __builtin_amdgcn_s_setprio(0);

#pragma unroll
    for (int kt = 0; kt < 2; kt++) {
      // --- softmax numerator in registers; lane's key k = (g&3)+8*(g>>2)+4*hi
      float p[16];
      if (allone) {
#pragma unroll
        for (int g = 0; g < 16; g++) p[g] = __builtin_amdgcn_exp2f(sa[kt][g]);
      } else {
#pragma unroll
        for (int g = 0; g < 16; g++) {
          const int k = kt * 32 + (g & 3) + 8 * (g >> 2) + 4 * hi;
          const float s = ((bm >> k) & 1) ? sa[kt][g] : CM;
          p[g] = __builtin_amdgcn_exp2f(s);
        }
      }
      // pack pairs: wd[g][i] = bf16x2 of keys {8g+4hi+2i, +1} (local to kt tile)
      unsigned wd[4][2];
#pragma unroll
      for (int g = 0; g < 4; g++) {
        wd[g][0] = cvt_pk_bf16(p[4 * g + 0], p[4 * g + 1]);
        wd[g][1] = cvt_pk_bf16(p[4 * g + 2], p[4 * g + 3]);
      }
      // --- redistribute into PV A-fragments (two 16-key chunks per kt) ---
#pragma unroll
      for (int c = 0; c < 2; c++) {
        plswap(wd[2 * c][0], wd[2 * c + 1][0]);  // -> words 0 and 2
        plswap(wd[2 * c][1], wd[2 * c + 1][1]);  // -> words 1 and 3
        union { unsigned u[4]; bf16x8 v; } pa;
        pa.u[0] = wd[2 * c][0];
        pa.u[1] = wd[2 * c][1];
        pa.u[2] = wd[2 * c + 1][0];
        pa.u[3] = wd[2 * c + 1][1];
        const int cg = kt * 2 + c;  // global 16-key chunk in [0,4)
        __builtin_amdgcn_s_setprio(1);
#pragma unroll
        for (int dt = 0; dt < 2; dt++) {
          const int rv = dt * 32 + lq;
          bf16x8 bv = *(const bf16x8*)&Vs[cur][(rv * 8 + ((2 * cg + hi) ^ rx)) * 8];
          o[dt] = __builtin_amdgcn_mfma_f32_32x32x16_bf16(pa.v, bv, o[dt], 0, 0, 0);
        }
        den = __builtin_amdgcn_mfma_f32_32x32x16_bf16(pa.v, ones.v, den, 0, 0, 0);
        __builtin_amdgcn_s_setprio(0);
      }
    }
  }

  // epilogue: C layout row=(g&3)+8*(g>>2)+4*hi, col=lq (+32 for dt=1)
  u16* cb = ctx + (long)b * (2048L * 1024) + (q0 + w * 32) * 1024 + h * 64;
#pragma unroll
  for (int g = 0; g < 16; g++) {
    const int row = (g & 3) + 8 * (g >> 2) + 4 * hi;
    const float inv = 1.0f / den[g];
    cb[(long)row * 1024 + lq] = f2bf(o[0][g] * inv);
    cb[(long)row * 1024 + 32 + lq] = f2bf(o[1][g] * inv);
  }
}

// LayerNorm over D=1024 (ddof=1) -> bf16
__device__ __forceinline__ void ln_row(const float* __restrict__ x, u16* __restrict__ y,
                                       const float* __restrict__ g, const float* __restrict__ b,
                                       long row, float* ss, float* s2) {
  const float* xr = x + row * 1024;
  float v[4];
  float s = 0.f, sq = 0.f;
#pragma unroll
  for (int i = 0; i < 4; i++) {
    float f = xr[threadIdx.x + i * 256];
    v[i] = f; s += f; sq += f * f;
  }
#pragma unroll
  for (int o = 32; o > 0; o >>= 1) { s += __shfl_xor(s, o, 64); sq += __shfl_xor(sq, o, 64); }
  const int w = threadIdx.x >> 6;
  if ((threadIdx.x & 63) == 0) { ss[w] = s; s2[w] = sq; }
  __syncthreads();
  s = ss[0] + ss[1] + ss[2] + ss[3];
  sq = s2[0] + s2[1] + s2[2] + s2[3];
  const float mean = s * (1.0f / 1024.0f);
  float var = (sq - s * mean) * (1.0f / 1023.0f);
  var = fmaxf(var, 0.0f);
  const float sc = g[0] / (sqrtf(var) + 1e-6f);
  const float be = b[0];
#pragma unroll
  for (int i = 0; i < 4; i++)
    y[row * 1024 + threadIdx.x + i * 256] = f2bf((v[i] - mean) * sc + be);
}

__global__ __launch_bounds__(256) void ln_kernel(const float* __restrict__ x, u16* __restrict__ y,
                                                 const float* __restrict__ g, const float* __restrict__ b) {
  __shared__ float ss[4], s2[4];
  ln_row(x, y, g, b, blockIdx.x, ss, s2);
}

// ---------------------------------------------------------------------------
// Fused prep: all 6 weight transposes (fp32 -> transposed bf16), bias concat,
// and LN1 — one dispatch.
// ---------------------------------------------------------------------------
__global__ __launch_bounds__(256) void prep_kernel(
    const float* __restrict__ x, const float* __restrict__ g1, const float* __restrict__ be1,
    const float* __restrict__ wq, const float* __restrict__ wk, const float* __restrict__ wv,
    const float* __restrict__ wo, const float* __restrict__ w1, const float* __restrict__ w2,
    const float* __restrict__ bq, const float* __restrict__ bk, const float* __restrict__ bv,
    u16* __restrict__ xnH, u16* __restrict__ WqkvT, u16* __restrict__ woT,
    u16* __restrict__ w1T, u16* __restrict__ w2T, float* __restrict__ biasQKV) {
  __shared__ float tile[32][33];
  __shared__ float ss[4], s2[4];
  const int bid = blockIdx.x;
  if (bid >= 12300) {  // LN1
    ln_row(x, xnH, g1, be1, bid - 12300, ss, s2);
    return;
  }
  if (bid >= 12288) {  // bias concat
    const int i = (bid - 12288) * 256 + threadIdx.x;
    if (i < 3072) biasQKV[i] = (i < 1024) ? bq[i] : ((i < 2048) ? bk[i - 1024] : bv[i - 2048]);
    return;
  }
  const float* in; u16* out; long ldin, ldo; int ti, tiles_x;
  if (bid < 1024)      { in = wq; out = WqkvT;                     ldin = 1024; ldo = 1024; ti = bid;        tiles_x = 32; }
  else if (bid < 2048) { in = wk; out = WqkvT + (size_t)1024*1024; ldin = 1024; ldo = 1024; ti = bid - 1024; tiles_x = 32; }
  else if (bid < 3072) { in = wv; out = WqkvT + (size_t)2048*1024; ldin = 1024; ldo = 1024; ti = bid - 2048; tiles_x = 32; }
  else if (bid < 4096) { in = wo; out = woT;                       ldin = 1024; ldo = 1024; ti = bid - 3072; tiles_x = 32; }
  else if (bid < 8192) { in = w1; out = w1T;                       ldin = 4096; ldo = 1024; ti = bid - 4096; tiles_x = 128; }
  else                 { in = w2; out = w2T;                       ldin = 1024; ldo = 4096; ti = bid - 8192; tiles_x = 32; }
  const int bx = (ti % tiles_x) * 32, by = (ti / tiles_x) * 32;
  const int tx = threadIdx.x & 31, ty = threadIdx.x >> 5;
#pragma unroll
  for (int i = 0; i < 32; i += 8) tile[ty + i][tx] = in[(long)(by + ty + i) * ldin + bx + tx];
  __syncthreads();
#pragma unroll
  for (int i = 0; i < 32; i += 8)
    out[(long)(bx + ty + i) * ldo + by + tx] = f2bf(tile[tx][ty + i]);
}

// bf16 [R][C] -> transposed [C][R], batched over z
__global__ __launch_bounds__(256) void ttrans1(const u16* __restrict__ in, long ldin, long siz,
                                               u16* __restrict__ out, long ldo, long soz) {
  __shared__ u16 tile[32][33];
  const long zi = (long)blockIdx.z * siz, zo = (long)blockIdx.z * soz;
  const int bx = blockIdx.x * 32, by = blockIdx.y * 32;
  const int tx = threadIdx.x & 31, ty = threadIdx.x >> 5;
#pragma unroll
  for (int i = 0; i < 32; i += 8)
    tile[ty + i][tx] = in[zi + (long)(by + ty + i) * ldin + bx + tx];
  __syncthreads();
#pragma unroll
  for (int i = 0; i < 32; i += 8)
    out[zo + (long)(bx + ty + i) * ldo + by + tx] = tile[tx][ty + i];
}

extern "C" void kernel_launch(void* const* d_in, const int* in_sizes, int n_in,
                              void* d_out, int out_size, void* d_ws, size_t ws_size,
                              hipStream_t stream) {
  const float* x   = (const float*)d_in[0];
  const int*   msk = (const int*)d_in[1];
  const float* wq  = (const float*)d_in[2];
  const float* bq  = (const float*)d_in[3];
  const float* wk  = (const float*)d_in[4];
  const float* bk  = (const float*)d_in[5];
  const float* wv  = (const float*)d_in[6];
  const float* bv  = (const float*)d_in[7];
  const float* wo  = (const float*)d_in[8];
  const float* bo  = (const float*)d_in[9];
  const float* w1  = (const float*)d_in[10];
  const float* b1  = (const float*)d_in[11];
  const float* w2  = (const float*)d_in[12];
  const float* b2  = (const float*)d_in[13];
  const float* g1  = (const float*)d_in[14];
  const float* be1 = (const float*)d_in[15];
  const float* g2  = (const float*)d_in[16];
  const float* be2 = (const float*)d_in[17];
  float* out = (float*)d_out;

  char* basep = (char*)d_ws;
  size_t off = 0;
  auto au = [&](size_t nelem) -> u16* {
    u16* r = (u16*)(basep + off);
    off += ((nelem * 2) + 255) & ~(size_t)255;
    return r;
  };
  auto afp = [&](size_t nelem) -> float* {
    float* r = (float*)(basep + off);
    off += ((nelem * 4) + 255) & ~(size_t)255;
    return r;
  };

  u16* xnH  = au((size_t)4096 * 1024);
  u16* QKV  = au((size_t)4096 * 3072);
  u16* VTH  = au((size_t)2 * 1024 * 2048);
  u16* ctxH = au((size_t)4096 * 1024);
  float* x1 = afp((size_t)4096 * 1024);
  u16* hb   = au((size_t)4096 * 4096);
  u16* WqkvT = au((size_t)3072 * 1024);
  u16* woT  = au((size_t)1024 * 1024);
  u16* w1T  = au((size_t)4096 * 1024);
  u16* w2T  = au((size_t)1024 * 4096);
  float* biasQKV = afp(3072);

  const dim3 blk(256);
  const dim3 blk5(512);

  // prep: LN1 + all weight transposes + bias concat (one dispatch)
  prep_kernel<<<16396, blk, 0, stream>>>(x, g1, be1, wq, wk, wv, wo, w1, w2,
                                         bq, bk, bv, xnH, WqkvT, woT, w1T, w2T, biasQKV);

  // QKV = xn @ WqkvT^T + bias -> bf16 [4096][3072]  (deep-pipelined)
  gemm3<2><<<dim3(16, 24), blk5, 0, stream>>>(
      xnH, 1024, WqkvT, 1024, QKV, 3072, 1024,
      biasQKV, (const float*)0, 0, 0);

  // VT[b][1024][2048] from V section (cols 2048..3071 of QKV)
  ttrans1<<<dim3(32, 64, 2), blk, 0, stream>>>(
      QKV + 2048, 3072, (long)2048 * 3072, VTH, 2048, (long)1024 * 2048);

  // fused attention -> ctxH
  flash_attn<<<dim3(16, 1, 32), blk, 0, stream>>>(QKV, VTH, msk, ctxH);

  // x1 = ctx @ woT^T + bo + x  (fp32; BK=64)
  gemm_bt<128, 64, 64, 0><<<dim3(32, 16), blk, 0, stream>>>(
      ctxH, 1024, woT, 1024, x1, 1024, 1024, 1.0f, bo, x, 1024, 0);

  // LN2 -> xnH
  ln_kernel<<<4096, blk, 0, stream>>>(x1, xnH, g2, be2);

  // FFN1: relu(xn @ w1T^T + b1) -> hb (bf16)  (deep-pipelined)
  gemm3<2><<<dim3(16, 32), blk5, 0, stream>>>(
      xnH, 1024, w1T, 1024, hb, 4096, 1024,
      b1, (const float*)0, 0, 1);

  // FFN2: hb @ w2T^T + b2 + x1 -> out (fp32; BK=64)
  gemm_bt<128, 64, 64, 0><<<dim3(32, 16), blk, 0, stream>>>(
      hb, 4096, w2T, 4096, out, 1024, 4096, 1.0f, b2, x1, 1024, 0);
}

// Round 4
// 343.128 us; speedup vs baseline: 1.0656x; 1.0656x over previous
//
#include <hip/hip_runtime.h>

typedef unsigned short u16;
typedef __bf16 bf16x8 __attribute__((ext_vector_type(8)));
typedef float f32x4 __attribute__((ext_vector_type(4)));
typedef float f32x16 __attribute__((ext_vector_type(16)));

#define AS1U(p) ((__attribute__((address_space(1))) unsigned int*)(p))
#define AS3U(p) ((__attribute__((address_space(3))) unsigned int*)(p))

__device__ __forceinline__ u16 f2bf(float f) {  // round-to-nearest-even
  union { float f; unsigned int i; } c; c.f = f;
  return (u16)((c.i + 0x7FFFu + ((c.i >> 16) & 1u)) >> 16);
}
__device__ __forceinline__ u16 f2bf_trunc(float f) {
  union { float f; unsigned int i; } c; c.f = f;
  return (u16)(c.i >> 16);
}
// pack two f32 -> bf16x2 word (no builtin on gfx950; RNE)
__device__ __forceinline__ unsigned cvt_pk_bf16(float lo, float hi) {
  unsigned r;
  asm("v_cvt_pk_bf16_f32 %0, %1, %2" : "=v"(r) : "v"(lo), "v"(hi));
  return r;
}
// swap a's upper 32 lanes with b's lower 32 lanes (both modified)
__device__ __forceinline__ void plswap(unsigned& a, unsigned& b) {
  asm("v_permlane32_swap_b32 %0, %1" : "+v"(a), "+v"(b));
}

// ---------------------------------------------------------------------------
// 8-phase GEMM (m201 port): C = A @ Bt^T + bias (+relu, +res). 256x256 tile,
// BK=64, 512 threads = 8 waves (2M x 4N), per-wave 128x64, 32x32x16 MFMA.
// Double-buffered LDS (128 KB). Each K-tile = 4 phases; phase mi:
//   {ds_read a[mi] (4 b128; +8 B-reads at mi=0, B cached in regs all tile)
//    | stage ONE 16KB half-tile | barrier | 8 MFMA | barrier}.
// Stage stagger (unit staged -> consumed): B0(t+1)@(t-1,ph3), B1(t+1)@(t,ph0),
// A0(t+1)@(t,ph1), A1(t+1)@(t,ph2), B0(t+2)@(t,ph3). Once-per-tile wait at
// ph3 = vmcnt(2): completes t+1's units, leaves B0(t+2) in flight — never
// drains in steady state (T3+T4). Write/read races barrier-checked:
// B-region reads finish at ph0, A at ph3; every conflicting stage issues
// >=1 barrier after the last reader. chunk^(row&7) 16B swizzle both sides.
// K % 64 == 0, K/64 >= 2. OMODE: 0 fp32 out, 2 bf16 out.
// ---------------------------------------------------------------------------
template <int OMODE>
__global__ __launch_bounds__(512, 2) void gemm8(
    const u16* __restrict__ A, long lda,
    const u16* __restrict__ B, long ldb,
    void* __restrict__ Cv, long ldc,
    int K, const float* __restrict__ bias,
    const float* __restrict__ res, long ldres, int relu) {
  __shared__ u16 As[2][256 * 64];
  __shared__ u16 Bs[2][256 * 64];
  const int t = threadIdx.x;
  const int w = t >> 6, l = t & 63;
  const int hi = l >> 5, lq = l & 31;
  const int wm = w >> 2, wn = w & 3;  // 2M x 4N
  const long row0 = (long)blockIdx.x * 256;
  const long col0 = (long)blockIdx.y * 256;

  // unit: 0 = B rows 0-127, 1 = B rows 128-255, 2 = A rows 0-127, 3 = A rows 128-255
  auto stageU = [&](int bb, int unit, int k0) {
    const u16* src = (unit < 2) ? B : A;
    const long ld = (unit < 2) ? ldb : lda;
    const long base0 = (unit < 2) ? col0 : row0;
    u16* dst = (unit < 2) ? &Bs[bb][0] : &As[bb][0];
    const int h = unit & 1;
#pragma unroll
    for (int i = 0; i < 2; i++) {
      int s = t + i * 512;  // 0..1023
      int r = h * 128 + (s >> 3), c = s & 7;
      __builtin_amdgcn_global_load_lds(AS1U(src + (base0 + r) * ld + k0 + ((c ^ (r & 7)) * 8)),
                                       AS3U(dst + ((long)(r * 8 + c)) * 8), 16, 0, 0);
    }
  };

  f32x16 acc[4][2] = {};
  const int NT = K >> 6;

  // prologue: tile0's 4 units + B0(1); wait leaves B0(1) in flight
  stageU(0, 0, 0); stageU(0, 1, 0); stageU(0, 2, 0); stageU(0, 3, 0);
  if (NT > 1) stageU(1, 0, 64);
  asm volatile("s_waitcnt vmcnt(2)" ::: "memory");
  __builtin_amdgcn_sched_barrier(0);
  __builtin_amdgcn_s_barrier();
  __builtin_amdgcn_sched_barrier(0);

  bf16x8 bfr[2][4];
  for (int tt = 0; tt < NT; tt++) {
    const int cb = tt & 1, nb = cb ^ 1;
    const int kN = (tt + 1) << 6, kN2 = (tt + 2) << 6;
#pragma unroll
    for (int mi = 0; mi < 4; mi++) {
      bf16x8 afr[4];
      {
        const int r = wm * 128 + mi * 32 + lq;
#pragma unroll
        for (int kk = 0; kk < 4; kk++)
          afr[kk] = *(const bf16x8*)&As[cb][(r * 8 + ((kk * 2 + hi) ^ (r & 7))) * 8];
      }
      if (mi == 0) {
#pragma unroll
        for (int nj = 0; nj < 2; nj++) {
          const int r = wn * 64 + nj * 32 + lq;
#pragma unroll
          for (int kk = 0; kk < 4; kk++)
            bfr[nj][kk] = *(const bf16x8*)&Bs[cb][(r * 8 + ((kk * 2 + hi) ^ (r & 7))) * 8];
        }
      }
      // one half-tile stage per phase (staggered; see header comment)
      if (mi == 0) { if (tt + 1 < NT) stageU(nb, 1, kN); }
      else if (mi == 1) { if (tt + 1 < NT) stageU(nb, 2, kN); }
      else if (mi == 2) { if (tt + 1 < NT) stageU(nb, 3, kN); }
      else {
        if (tt + 2 < NT) stageU(cb, 0, kN2);
        if (tt < NT - 2) asm volatile("s_waitcnt vmcnt(2)" ::: "memory");
        else             asm volatile("s_waitcnt vmcnt(0)" ::: "memory");
      }
      __builtin_amdgcn_sched_barrier(0);
      __builtin_amdgcn_s_barrier();
      __builtin_amdgcn_sched_barrier(0);
      __builtin_amdgcn_s_setprio(1);
#pragma unroll
      for (int kk = 0; kk < 4; kk++)
#pragma unroll
        for (int nj = 0; nj < 2; nj++)
          acc[mi][nj] = __builtin_amdgcn_mfma_f32_32x32x16_bf16(afr[kk], bfr[nj][kk], acc[mi][nj], 0, 0, 0);
      __builtin_amdgcn_s_setprio(0);
      __builtin_amdgcn_sched_barrier(0);
      __builtin_amdgcn_s_barrier();
      __builtin_amdgcn_sched_barrier(0);
    }
  }

  // epilogue: C layout col=lq, row=(g&3)+8*(g>>2)+4*hi per 32x32 tile
#pragma unroll
  for (int nj = 0; nj < 2; nj++) {
    const long gn = col0 + wn * 64 + nj * 32 + lq;
    const float bv = bias ? bias[gn] : 0.0f;
#pragma unroll
    for (int mi = 0; mi < 4; mi++) {
#pragma unroll
      for (int g = 0; g < 16; g++) {
        const long gm = row0 + wm * 128 + mi * 32 + (g & 3) + 8 * (g >> 2) + 4 * hi;
        float v = acc[mi][nj][g] + bv;
        if (relu && v < 0.0f) v = 0.0f;
        if (res) v += res[gm * ldres + gn];
        if (OMODE == 0) ((float*)Cv)[gm * ldc + gn] = v;
        else ((u16*)Cv)[gm * ldc + gn] = f2bf(v);
      }
    }
  }
}

// ---------------------------------------------------------------------------
// C = scale*(A @ Bt^T) + bias (+relu, +res). Single-plane bf16, 1 MFMA/product.
// Double-buffered K-loop. BK=32: m97-plain LDS (64B rows). BK=64: flash-style
// 128B rows with chunk^(row&7) swizzle (measured conflict-free) — halves the
// barrier count vs BK=32. K % (2*BK) == 0. OMODE: 0 = fp32 out, 2 = bf16 out.
// ---------------------------------------------------------------------------
template <int BM, int BN, int BK, int OMODE>
__global__ __launch_bounds__(256) void gemm_bt(
    const u16* __restrict__ A, long lda,
    const u16* __restrict__ B, long ldb,
    void* __restrict__ Cv, long ldc,
    int K, float scale, const float* __restrict__ bias,
    const float* __restrict__ res, long ldres, int relu) {
  constexpr int WN = (BN == 128) ? 64 : 32;
  constexpr int MI = 4, NJ = WN / 16;
  constexpr int KK = BK / 32;  // k-chunks per stage
  __shared__ u16 As0[BM * BK], As1[BM * BK];
  __shared__ u16 Bs0[BN * BK], Bs1[BN * BK];
  const int t = threadIdx.x;
  const int w = t >> 6, l = t & 63;
  const int wr = w >> 1, wc = w & 1;
  const int quad = l >> 4, mlo = l & 15;
  const long row0 = (long)blockIdx.x * BM;
  const long col0 = (long)blockIdx.y * BN;

  f32x4 acc[MI][NJ] = {};

  auto stage = [&](u16 (&Ad)[BM * BK], u16 (&Bd)[BN * BK], int k0) {
    if (BK == 32) {
#pragma unroll
      for (int i = 0; i < BM / 64; i++) {
        int s = t + i * 256, r = s >> 2, c = s & 3;
        const u16* g = A + (row0 + r) * lda + k0 + c * 8;
        __builtin_amdgcn_global_load_lds(AS1U(g), AS3U(&Ad[s * 8]), 16, 0, 0);
      }
#pragma unroll
      for (int i = 0; i < BN / 64; i++) {
        int s = t + i * 256, r = s >> 2, c = s & 3;
        const u16* g = B + (col0 + r) * ldb + k0 + c * 8;
        __builtin_amdgcn_global_load_lds(AS1U(g), AS3U(&Bd[s * 8]), 16, 0, 0);
      }
    } else {  // BK == 64: 128B rows, chunk^(r&7) swizzle
#pragma unroll
      for (int i = 0; i < BM / 32; i++) {
        int s = t + i * 256, r = s >> 3, c = s & 7;
        const u16* g = A + (row0 + r) * lda + k0 + (c ^ (r & 7)) * 8;
        __builtin_amdgcn_global_load_lds(AS1U(g), AS3U(&Ad[s * 8]), 16, 0, 0);
      }
#pragma unroll
      for (int i = 0; i < BN / 32; i++) {
        int s = t + i * 256, r = s >> 3, c = s & 7;
        const u16* g = B + (col0 + r) * ldb + k0 + (c ^ (r & 7)) * 8;
        __builtin_amdgcn_global_load_lds(AS1U(g), AS3U(&Bd[s * 8]), 16, 0, 0);
      }
    }
  };
  auto compute = [&](const u16 (&Asr)[BM * BK], const u16 (&Bsr)[BN * BK]) {
#pragma unroll
    for (int kk = 0; kk < KK; kk++) {
      bf16x8 a[MI], b[NJ];
#pragma unroll
      for (int i = 0; i < MI; i++) {
        int r = wr * 64 + i * 16 + mlo;
        a[i] = (BK == 32) ? *(const bf16x8*)&Asr[(r * 4 + quad) * 8]
                          : *(const bf16x8*)&Asr[(r * 8 + ((kk * 4 + quad) ^ (r & 7))) * 8];
      }
#pragma unroll
      for (int j = 0; j < NJ; j++) {
        int r = wc * WN + j * 16 + mlo;
        b[j] = (BK == 32) ? *(const bf16x8*)&Bsr[(r * 4 + quad) * 8]
                          : *(const bf16x8*)&Bsr[(r * 8 + ((kk * 4 + quad) ^ (r & 7))) * 8];
      }
#pragma unroll
      for (int i = 0; i < MI; i++)
#pragma unroll
        for (int j = 0; j < NJ; j++)
          acc[i][j] = __builtin_amdgcn_mfma_f32_16x16x32_bf16(a[i], b[j], acc[i][j], 0, 0, 0);
    }
  };

  stage(As0, Bs0, 0);
  for (int k0 = 0; k0 < K; k0 += 2 * BK) {
    __syncthreads();
    stage(As1, Bs1, k0 + BK);
    compute(As0, Bs0);
    __syncthreads();
    if (k0 + 2 * BK < K) stage(As0, Bs0, k0 + 2 * BK);
    compute(As1, Bs1);
  }

#pragma unroll
  for (int i = 0; i < MI; i++) {
#pragma unroll
    for (int j = 0; j < NJ; j++) {
      const long gn = col0 + wc * WN + j * 16 + mlo;
      const float bv = bias ? bias[gn] : 0.0f;
#pragma unroll
      for (int r = 0; r < 4; r++) {
        const long gm = row0 + wr * 64 + i * 16 + quad * 4 + r;
        float v = acc[i][j][r] * scale + bv;
        if (relu && v < 0.0f) v = 0.0f;
        if (res) v += res[gm * ldres + gn];
        if (OMODE == 0) ((float*)Cv)[gm * ldc + gn] = v;
        else ((u16*)Cv)[gm * ldc + gn] = f2bf(v);
      }
    }
  }
}

// ---------------------------------------------------------------------------
// Fused flash attention, in-register softmax (T12). Br=128, Bc=64, DK=64.
// Swapped QK^T via mfma_f32_32x32x16_bf16: S^T = K·Q^T so each lane holds a
// lane-local slice (16 of 32 keys per k-tile) of ONE q-row (q = lane&31).
// P never touches LDS: exp2 in f32 regs -> v_cvt_pk_bf16_f32 pairs ->
// v_permlane32_swap_b32 redistributes straight into the PV A-fragment layout.
// Q pre-scaled by 1/8*log2e; mask all-ones bitmap precomputed in prologue;
// both kt score tiles computed back-to-back so SM VALU hides under MFMAs.
// LDS 32 KB (K,V double-buffered only); one barrier/iter.
// ---------------------------------------------------------------------------
__global__ __launch_bounds__(256, 2) void flash_attn(
    const u16* __restrict__ QKV, const u16* __restrict__ VT,
    const int* __restrict__ mask, u16* __restrict__ ctx) {
  __shared__ u16 Ks[2][64 * 64];
  __shared__ u16 Vs[2][64 * 64];
  const int t = threadIdx.x;
  const int w = t >> 6, l = t & 63;
  const int hi = l >> 5, lq = l & 31, rx = lq & 7;
  const int z = blockIdx.z, b = z >> 4, h = z & 15;
  const long q0 = (long)blockIdx.x * 128;
  const u16* Qg = QKV + (long)b * (2048L * 3072) + h * 64;
  const u16* Kg = Qg + 1024;
  const u16* Vg = VT + (long)b * (1024L * 2048) + (long)(h * 64) * 2048;
  const int* mrow = mask + b * 2048;

#pragma unroll
  for (int i = 0; i < 2; i++) {
    int s = t + i * 256, r = s >> 3, c = s & 7;
    __builtin_amdgcn_global_load_lds(AS1U(Kg + (long)r * 3072 + (c ^ (r & 7)) * 8),
                                     AS3U(&Ks[0][s * 8]), 16, 0, 0);
    __builtin_amdgcn_global_load_lds(AS1U(Vg + (long)r * 2048 + (c ^ (r & 7)) * 8),
                                     AS3U(&Vs[0][s * 8]), 16, 0, 0);
  }

  const float CS = 0.125f * 1.44269504f;  // 1/sqrt(64) * log2(e)
  const float CM = -1.44269504f;          // MASK_FILL(-1) * log2(e)

  // Q as QK^T B-fragments, PRE-SCALED by CS: lane holds Q[q=lq][kk*16+hi*8+e]
  bf16x8 aq[4];
#pragma unroll
  for (int kk = 0; kk < 4; kk++) {
    const u16* g = Qg + (q0 + w * 32 + lq) * 3072 + kk * 16 + hi * 8;
    union { uint4 u; bf16x8 v; u16 s[8]; } cc; cc.u = *(const uint4*)g;
#pragma unroll
    for (int e = 0; e < 8; e++) {
      union { unsigned u; float f; } qf; qf.u = (unsigned)cc.s[e] << 16;
      cc.s[e] = f2bf(qf.f * CS);
    }
    aq[kk] = cc.v;
  }

  // prologue mask bitmap: bit it == 1 -> all 64 keys of tile `it` unmasked
  unsigned am = 0;
  for (int it = 0; it < 32; ++it) {
    unsigned long long bmv = __ballot(mrow[it * 64 + l] != 0);
    am |= ((bmv == ~0ull) ? 1u : 0u) << it;
  }

  f32x16 o[2] = {}, den = {};
  union { u16 s[8]; bf16x8 v; } ones;
#pragma unroll
  for (int e = 0; e < 8; e++) ones.s[e] = 0x3F80;

  for (int it = 0; it < 32; ++it) {
    const int cur = it & 1;
    __syncthreads();
    if (it + 1 < 32) {
      const int nb = 1 - cur;
      const u16* Kg2 = Kg + (long)(it + 1) * 64 * 3072;
      const u16* Vg2 = Vg + (it + 1) * 64;
#pragma unroll
      for (int i2 = 0; i2 < 2; i2++) {
        int s = t + i2 * 256, r = s >> 3, c = s & 7;
        __builtin_amdgcn_global_load_lds(AS1U(Kg2 + (long)r * 3072 + (c ^ (r & 7)) * 8),
                                         AS3U(&Ks[nb][s * 8]), 16, 0, 0);
        __builtin_amdgcn_global_load_lds(AS1U(Vg2 + (long)r * 2048 + (c ^ (r & 7)) * 8),
                                         AS3U(&Vs[nb][s * 8]), 16, 0, 0);
      }
    }
    const bool allone = (am >> it) & 1u;
    unsigned long long bm = ~0ull;
    if (!allone) bm = __ballot(mrow[it * 64 + l] != 0);  // rare slow path

    // --- QK^T (swapped) for BOTH kt tiles: S^T[k][q]; A = K rows, B = Q ---
    f32x16 sa[2];
    __builtin_amdgcn_s_setprio(1);
#pragma unroll
    for (int kt = 0; kt < 2; kt++) {
      f32x16 s0 = {};
      const int rk = kt * 32 + lq;
#pragma unroll
      for (int kk = 0; kk < 4; kk++) {
        bf16x8 ak = *(const bf16x8*)&Ks[cur][(rk * 8 + ((2 * kk + hi) ^ rx)) * 8];
        s0 = __builtin_amdgcn_mfma_f32_32x32x16_bf16(ak, aq[kk], s0, 0, 0, 0);
      }
      sa[kt] = s0;
    }
    __builtin_amdgcn_s_setprio(0);

#pragma unroll
    for (int kt = 0; kt < 2; kt++) {
      // --- softmax numerator in registers; lane's key k = (g&3)+8*(g>>2)+4*hi
      float p[16];
      if (allone) {
#pragma unroll
        for (int g = 0; g < 16; g++) p[g] = __builtin_amdgcn_exp2f(sa[kt][g]);
      } else {
#pragma unroll
        for (int g = 0; g < 16; g++) {
          const int k = kt * 32 + (g & 3) + 8 * (g >> 2) + 4 * hi;
          const float s = ((bm >> k) & 1) ? sa[kt][g] : CM;
          p[g] = __builtin_amdgcn_exp2f(s);
        }
      }
      // pack pairs: wd[g][i] = bf16x2 of keys {8g+4hi+2i, +1} (local to kt tile)
      unsigned wd[4][2];
#pragma unroll
      for (int g = 0; g < 4; g++) {
        wd[g][0] = cvt_pk_bf16(p[4 * g + 0], p[4 * g + 1]);
        wd[g][1] = cvt_pk_bf16(p[4 * g + 2], p[4 * g + 3]);
      }
      // --- redistribute into PV A-fragments (two 16-key chunks per kt) ---
#pragma unroll
      for (int c = 0; c < 2; c++) {
        plswap(wd[2 * c][0], wd[2 * c + 1][0]);  // -> words 0 and 2
        plswap(wd[2 * c][1], wd[2 * c + 1][1]);  // -> words 1 and 3
        union { unsigned u[4]; bf16x8 v; } pa;
        pa.u[0] = wd[2 * c][0];
        pa.u[1] = wd[2 * c][1];
        pa.u[2] = wd[2 * c + 1][0];
        pa.u[3] = wd[2 * c + 1][1];
        const int cg = kt * 2 + c;  // global 16-key chunk in [0,4)
        __builtin_amdgcn_s_setprio(1);
#pragma unroll
        for (int dt = 0; dt < 2; dt++) {
          const int rv = dt * 32 + lq;
          bf16x8 bv = *(const bf16x8*)&Vs[cur][(rv * 8 + ((2 * cg + hi) ^ rx)) * 8];
          o[dt] = __builtin_amdgcn_mfma_f32_32x32x16_bf16(pa.v, bv, o[dt], 0, 0, 0);
        }
        den = __builtin_amdgcn_mfma_f32_32x32x16_bf16(pa.v, ones.v, den, 0, 0, 0);
        __builtin_amdgcn_s_setprio(0);
      }
    }
  }

  // epilogue: C layout row=(g&3)+8*(g>>2)+4*hi, col=lq (+32 for dt=1)
  u16* cb = ctx + (long)b * (2048L * 1024) + (q0 + w * 32) * 1024 + h * 64;
#pragma unroll
  for (int g = 0; g < 16; g++) {
    const int row = (g & 3) + 8 * (g >> 2) + 4 * hi;
    const float inv = 1.0f / den[g];
    cb[(long)row * 1024 + lq] = f2bf(o[0][g] * inv);
    cb[(long)row * 1024 + 32 + lq] = f2bf(o[1][g] * inv);
  }
}

// LayerNorm over D=1024 (ddof=1) -> bf16
__device__ __forceinline__ void ln_row(const float* __restrict__ x, u16* __restrict__ y,
                                       const float* __restrict__ g, const float* __restrict__ b,
                                       long row, float* ss, float* s2) {
  const float* xr = x + row * 1024;
  float v[4];
  float s = 0.f, sq = 0.f;
#pragma unroll
  for (int i = 0; i < 4; i++) {
    float f = xr[threadIdx.x + i * 256];
    v[i] = f; s += f; sq += f * f;
  }
#pragma unroll
  for (int o = 32; o > 0; o >>= 1) { s += __shfl_xor(s, o, 64); sq += __shfl_xor(sq, o, 64); }
  const int w = threadIdx.x >> 6;
  if ((threadIdx.x & 63) == 0) { ss[w] = s; s2[w] = sq; }
  __syncthreads();
  s = ss[0] + ss[1] + ss[2] + ss[3];
  sq = s2[0] + s2[1] + s2[2] + s2[3];
  const float mean = s * (1.0f / 1024.0f);
  float var = (sq - s * mean) * (1.0f / 1023.0f);
  var = fmaxf(var, 0.0f);
  const float sc = g[0] / (sqrtf(var) + 1e-6f);
  const float be = b[0];
#pragma unroll
  for (int i = 0; i < 4; i++)
    y[row * 1024 + threadIdx.x + i * 256] = f2bf((v[i] - mean) * sc + be);
}

__global__ __launch_bounds__(256) void ln_kernel(const float* __restrict__ x, u16* __restrict__ y,
                                                 const float* __restrict__ g, const float* __restrict__ b) {
  __shared__ float ss[4], s2[4];
  ln_row(x, y, g, b, blockIdx.x, ss, s2);
}

// ---------------------------------------------------------------------------
// Fused prep: all 6 weight transposes (fp32 -> transposed bf16), bias concat,
// and LN1 — one dispatch.
// ---------------------------------------------------------------------------
__global__ __launch_bounds__(256) void prep_kernel(
    const float* __restrict__ x, const float* __restrict__ g1, const float* __restrict__ be1,
    const float* __restrict__ wq, const float* __restrict__ wk, const float* __restrict__ wv,
    const float* __restrict__ wo, const float* __restrict__ w1, const float* __restrict__ w2,
    const float* __restrict__ bq, const float* __restrict__ bk, const float* __restrict__ bv,
    u16* __restrict__ xnH, u16* __restrict__ WqkvT, u16* __restrict__ woT,
    u16* __restrict__ w1T, u16* __restrict__ w2T, float* __restrict__ biasQKV) {
  __shared__ float tile[32][33];
  __shared__ float ss[4], s2[4];
  const int bid = blockIdx.x;
  if (bid >= 12300) {  // LN1
    ln_row(x, xnH, g1, be1, bid - 12300, ss, s2);
    return;
  }
  if (bid >= 12288) {  // bias concat
    const int i = (bid - 12288) * 256 + threadIdx.x;
    if (i < 3072) biasQKV[i] = (i < 1024) ? bq[i] : ((i < 2048) ? bk[i - 1024] : bv[i - 2048]);
    return;
  }
  const float* in; u16* out; long ldin, ldo; int ti, tiles_x;
  if (bid < 1024)      { in = wq; out = WqkvT;                     ldin = 1024; ldo = 1024; ti = bid;        tiles_x = 32; }
  else if (bid < 2048) { in = wk; out = WqkvT + (size_t)1024*1024; ldin = 1024; ldo = 1024; ti = bid - 1024; tiles_x = 32; }
  else if (bid < 3072) { in = wv; out = WqkvT + (size_t)2048*1024; ldin = 1024; ldo = 1024; ti = bid - 2048; tiles_x = 32; }
  else if (bid < 4096) { in = wo; out = woT;                       ldin = 1024; ldo = 1024; ti = bid - 3072; tiles_x = 32; }
  else if (bid < 8192) { in = w1; out = w1T;                       ldin = 4096; ldo = 1024; ti = bid - 4096; tiles_x = 128; }
  else                 { in = w2; out = w2T;                       ldin = 1024; ldo = 4096; ti = bid - 8192; tiles_x = 32; }
  const int bx = (ti % tiles_x) * 32, by = (ti / tiles_x) * 32;
  const int tx = threadIdx.x & 31, ty = threadIdx.x >> 5;
#pragma unroll
  for (int i = 0; i < 32; i += 8) tile[ty + i][tx] = in[(long)(by + ty + i) * ldin + bx + tx];
  __syncthreads();
#pragma unroll
  for (int i = 0; i < 32; i += 8)
    out[(long)(bx + ty + i) * ldo + by + tx] = f2bf(tile[tx][ty + i]);
}

// bf16 [R][C] -> transposed [C][R], batched over z
__global__ __launch_bounds__(256) void ttrans1(const u16* __restrict__ in, long ldin, long siz,
                                               u16* __restrict__ out, long ldo, long soz) {
  __shared__ u16 tile[32][33];
  const long zi = (long)blockIdx.z * siz, zo = (long)blockIdx.z * soz;
  const int bx = blockIdx.x * 32, by = blockIdx.y * 32;
  const int tx = threadIdx.x & 31, ty = threadIdx.x >> 5;
#pragma unroll
  for (int i = 0; i < 32; i += 8)
    tile[ty + i][tx] = in[zi + (long)(by + ty + i) * ldin + bx + tx];
  __syncthreads();
#pragma unroll
  for (int i = 0; i < 32; i += 8)
    out[zo + (long)(bx + ty + i) * ldo + by + tx] = tile[tx][ty + i];
}

extern "C" void kernel_launch(void* const* d_in, const int* in_sizes, int n_in,
                              void* d_out, int out_size, void* d_ws, size_t ws_size,
                              hipStream_t stream) {
  const float* x   = (const float*)d_in[0];
  const int*   msk = (const int*)d_in[1];
  const float* wq  = (const float*)d_in[2];
  const float* bq  = (const float*)d_in[3];
  const float* wk  = (const float*)d_in[4];
  const float* bk  = (const float*)d_in[5];
  const float* wv  = (const float*)d_in[6];
  const float* bv  = (const float*)d_in[7];
  const float* wo  = (const float*)d_in[8];
  const float* bo  = (const float*)d_in[9];
  const float* w1  = (const float*)d_in[10];
  const float* b1  = (const float*)d_in[11];
  const float* w2  = (const float*)d_in[12];
  const float* b2  = (const float*)d_in[13];
  const float* g1  = (const float*)d_in[14];
  const float* be1 = (const float*)d_in[15];
  const float* g2  = (const float*)d_in[16];
  const float* be2 = (const float*)d_in[17];
  float* out = (float*)d_out;

  char* basep = (char*)d_ws;
  size_t off = 0;
  auto au = [&](size_t nelem) -> u16* {
    u16* r = (u16*)(basep + off);
    off += ((nelem * 2) + 255) & ~(size_t)255;
    return r;
  };
  auto afp = [&](size_t nelem) -> float* {
    float* r = (float*)(basep + off);
    off += ((nelem * 4) + 255) & ~(size_t)255;
    return r;
  };

  u16* xnH  = au((size_t)4096 * 1024);
  u16* QKV  = au((size_t)4096 * 3072);
  u16* VTH  = au((size_t)2 * 1024 * 2048);
  u16* ctxH = au((size_t)4096 * 1024);
  float* x1 = afp((size_t)4096 * 1024);
  u16* hb   = au((size_t)4096 * 4096);
  u16* WqkvT = au((size_t)3072 * 1024);
  u16* woT  = au((size_t)1024 * 1024);
  u16* w1T  = au((size_t)4096 * 1024);
  u16* w2T  = au((size_t)1024 * 4096);
  float* biasQKV = afp(3072);

  const dim3 blk(256);
  const dim3 blk5(512);

  // prep: LN1 + all weight transposes + bias concat (one dispatch)
  prep_kernel<<<16396, blk, 0, stream>>>(x, g1, be1, wq, wk, wv, wo, w1, w2,
                                         bq, bk, bv, xnH, WqkvT, woT, w1T, w2T, biasQKV);

  // QKV = xn @ WqkvT^T + bias -> bf16 [4096][3072]  (8-phase)
  gemm8<2><<<dim3(16, 12), blk5, 0, stream>>>(
      xnH, 1024, WqkvT, 1024, QKV, 3072, 1024,
      biasQKV, (const float*)0, 0, 0);

  // VT[b][1024][2048] from V section (cols 2048..3071 of QKV)
  ttrans1<<<dim3(32, 64, 2), blk, 0, stream>>>(
      QKV + 2048, 3072, (long)2048 * 3072, VTH, 2048, (long)1024 * 2048);

  // fused attention -> ctxH
  flash_attn<<<dim3(16, 1, 32), blk, 0, stream>>>(QKV, VTH, msk, ctxH);

  // x1 = ctx @ woT^T + bo + x  (fp32; BK=64)
  gemm_bt<128, 64, 64, 0><<<dim3(32, 16), blk, 0, stream>>>(
      ctxH, 1024, woT, 1024, x1, 1024, 1024, 1.0f, bo, x, 1024, 0);

  // LN2 -> xnH
  ln_kernel<<<4096, blk, 0, stream>>>(x1, xnH, g2, be2);

  // FFN1: relu(xn @ w1T^T + b1) -> hb (bf16)  (8-phase)
  gemm8<2><<<dim3(16, 16), blk5, 0, stream>>>(
      xnH, 1024, w1T, 1024, hb, 4096, 1024,
      b1, (const float*)0, 0, 1);

  // FFN2: hb @ w2T^T + b2 + x1 -> out (fp32; BK=64)
  gemm_bt<128, 64, 64, 0><<<dim3(32, 16), blk, 0, stream>>>(
      hb, 4096, w2T, 4096, out, 1024, 4096, 1.0f, b2, x1, 1024, 0);
}